// Round 16
// baseline (152.327 us; speedup 1.0000x reference)
//
#include <hip/hip_runtime.h>

#define NN 16384      // H*W, 128x128
#define CINC 64

// ---------------------------------------------------------------------------
// k0: fold weights.
// ---------------------------------------------------------------------------
__global__ void gat_k0(const float* __restrict__ w_restore,
                       const float* __restrict__ b_gat,
                       const float* __restrict__ w_reduce,
                       const float* __restrict__ w_lin,
                       const float* __restrict__ att_src,
                       const float* __restrict__ att_dst,
                       float* __restrict__ rb, float* __restrict__ wredT,
                       float* __restrict__ S, float* __restrict__ D) {
    int t = threadIdx.x;
    if (t < 128) {
        int h = t >> 5, k = t & 31;
        float s = 0.f, d = 0.f;
        for (int c = 0; c < 32; ++c) {
            float wl = w_lin[(h * 32 + c) * 32 + k];
            s += att_src[h * 32 + c] * wl;
            d += att_dst[h * 32 + c] * wl;
        }
        S[t] = s; D[t] = d;
    } else if (t < 192) {
        int o = t - 128;
        float r = 0.f;
        for (int c = 0; c < 32; ++c) r += w_restore[o * 32 + c] * b_gat[c];
        rb[o] = r;
    }
    for (int idx = t; idx < 2048; idx += 256) {
        int k = idx & 31, c = idx >> 5;
        wredT[c * 32 + k] = w_reduce[k * 64 + c];
    }
}

// ---------------------------------------------------------------------------
// k1: reduce conv + attention logits. Strip = 64 nodes, 2048 blocks.
// Weights via uniform global reads (s_load / constant cache).
// ---------------------------------------------------------------------------
__global__ __launch_bounds__(256) void gat_k1(
        const float* __restrict__ x, const float* __restrict__ wredT,
        const float* __restrict__ S, const float* __restrict__ D,
        float* __restrict__ red_g, float* __restrict__ as_ws,
        float* __restrict__ ad_ws) {
    __shared__ float xs[4096];         // [c][nd] 64x64
    __shared__ float red_lds[32][64];  // [k][nd]

    int tid = threadIdx.x;
    int s = blockIdx.x;
    int b = s >> 8;
    int v0 = (s & 255) << 6;

    const float* xb = x + (size_t)b * CINC * NN + v0;
    for (int idx = tid; idx < 4096; idx += 256) {
        int c = idx >> 6, nd = idx & 63;
        xs[idx] = xb[(size_t)c * NN + nd];           // coalesced 256B rows
    }
    __syncthreads();

    int nd = tid & 63;
    int wv = __builtin_amdgcn_readfirstlane(tid >> 6);  // wave-uniform

    // ---- phase A: reduced features, 8 k-channels per wave-group ----
    {
        float a0 = 0.f, a1 = 0.f, a2 = 0.f, a3 = 0.f,
              a4 = 0.f, a5 = 0.f, a6 = 0.f, a7 = 0.f;
        const float* wt = wredT + wv * 8;            // uniform base
#pragma unroll 4
        for (int c = 0; c < 64; ++c) {
            float xc = xs[c * 64 + nd];
            const float* w = wt + c * 32;            // uniform -> s_load
            a0 = fmaf(w[0], xc, a0);
            a1 = fmaf(w[1], xc, a1);
            a2 = fmaf(w[2], xc, a2);
            a3 = fmaf(w[3], xc, a3);
            a4 = fmaf(w[4], xc, a4);
            a5 = fmaf(w[5], xc, a5);
            a6 = fmaf(w[6], xc, a6);
            a7 = fmaf(w[7], xc, a7);
        }
        int k0 = wv * 8;
        float* rg = red_g + (size_t)b * 32 * NN + v0 + nd;
        red_lds[k0 + 0][nd] = a0; rg[(size_t)(k0 + 0) * NN] = a0;
        red_lds[k0 + 1][nd] = a1; rg[(size_t)(k0 + 1) * NN] = a1;
        red_lds[k0 + 2][nd] = a2; rg[(size_t)(k0 + 2) * NN] = a2;
        red_lds[k0 + 3][nd] = a3; rg[(size_t)(k0 + 3) * NN] = a3;
        red_lds[k0 + 4][nd] = a4; rg[(size_t)(k0 + 4) * NN] = a4;
        red_lds[k0 + 5][nd] = a5; rg[(size_t)(k0 + 5) * NN] = a5;
        red_lds[k0 + 6][nd] = a6; rg[(size_t)(k0 + 6) * NN] = a6;
        red_lds[k0 + 7][nd] = a7; rg[(size_t)(k0 + 7) * NN] = a7;
    }
    __syncthreads();

    // ---- phase B: logits, head = wave; S/D via uniform s_load ----
    {
        float rv[32];
#pragma unroll
        for (int k = 0; k < 32; ++k) rv[k] = red_lds[k][nd];
        const float* sp = S + wv * 32;               // uniform base
        const float* dp = D + wv * 32;
        float pas = 0.f, pad_ = 0.f;
#pragma unroll
        for (int k = 0; k < 32; ++k) {
            pas  = fmaf(sp[k], rv[k], pas);
            pad_ = fmaf(dp[k], rv[k], pad_);
        }
        as_ws[((size_t)b * 4 + wv) * NN + v0 + nd] = pas;
        ad_ws[((size_t)b * 4 + wv) * NN + v0 + nd] = pad_;
    }
}

// ---------------------------------------------------------------------------
// k2: round-12 structure + MANUALLY SOFTWARE-PIPELINED kc loop: two named
//     register sets r0/r1; order L0,L1,F0,L2,F1,L3,F2,F3 -- each 256-FMA
//     fold covers the next 40-load batch (round-12's `unroll 1` exposed
//     4 full L2 latencies; round-13's "all racc first" let the compiler
//     re-serialize at 36 VGPR). Static names; live ~= gpart32+16r ~= 75 VGPR.
// ---------------------------------------------------------------------------
__global__ __launch_bounds__(256) void gat_k2(
        const float* __restrict__ x, const float* __restrict__ w_lin,
        const float* __restrict__ w_restore, const float* __restrict__ rb,
        const float* __restrict__ red_g, const float* __restrict__ as_ws,
        const float* __restrict__ ad_ws, float* __restrict__ outp,
        float* __restrict__ part) {
    __shared__ float gp[4][8][64];    // per-head partial, c-quarter: 8 KB
    __shared__ float gout[32][64];    // reduced g: 8 KB
    __shared__ float stat_lds[128];

    int tid = threadIdx.x;
    int s = blockIdx.x;
    int b = s >> 8;
    int v0 = (s & 255) << 6;
    int nd = tid & 63;
    int h = __builtin_amdgcn_readfirstlane(tid >> 6);  // wave-uniform head
    int v = v0 + nd;
    int i = v >> 7, j = v & 127;

    int un0 = v;
    int un1 = i > 0   ? v - 128 : v;
    int un2 = i < 127 ? v + 128 : v;
    int un3 = j > 0   ? v - 1   : v;
    int un4 = j < 127 ? v + 1   : v;

    // ---- alpha (regs only), head = wave ----
    float a0, a1, a2, a3, a4;
    {
        const float* asp = as_ws + ((size_t)b * 4 + h) * NN;
        float adv = ad_ws[((size_t)b * 4 + h) * NN + v];
        float e0 = asp[un0] + adv, e1 = asp[un1] + adv, e2 = asp[un2] + adv,
              e3 = asp[un3] + adv, e4 = asp[un4] + adv;
        e0 = e0 > 0.f ? e0 : 0.2f * e0;
        e1 = e1 > 0.f ? e1 : 0.2f * e1;
        e2 = e2 > 0.f ? e2 : 0.2f * e2;
        e3 = e3 > 0.f ? e3 : 0.2f * e3;
        e4 = e4 > 0.f ? e4 : 0.2f * e4;
        e1 += i > 0   ? 0.f : -1e30f;
        e2 += i < 127 ? 0.f : -1e30f;
        e3 += j > 0   ? 0.f : -1e30f;
        e4 += j < 127 ? 0.f : -1e30f;
        float m = fmaxf(fmaxf(fmaxf(e0, e1), fmaxf(e2, e3)), e4);
        e0 = __expf(e0 - m); e1 = __expf(e1 - m); e2 = __expf(e2 - m);
        e3 = __expf(e3 - m); e4 = __expf(e4 - m);
        float sc = 0.25f / (e0 + e1 + e2 + e3 + e4);   // fold head-mean
        a0 = e0 * sc; a1 = e1 * sc; a2 = e2 * sc; a3 = e3 * sc; a4 = e4 * sc;
    }

    // ---- software-pipelined stencil + SGPR fold ----
    float gpart[32];
#pragma unroll
    for (int c = 0; c < 32; ++c) gpart[c] = 0.f;

    const float* rp = red_g + (size_t)b * 32 * NN;
    const float* wl_h = w_lin + (size_t)h * 32 * 32;   // SGPR base

#define STEN8(dst, KC)                                                       \
    {                                                                        \
        _Pragma("unroll")                                                    \
        for (int i8 = 0; i8 < 8; ++i8) {                                     \
            const float* rk = rp + (size_t)((KC) * 8 + i8) * NN;             \
            dst[i8] = a0 * rk[un0] + a1 * rk[un1] + a2 * rk[un2] +           \
                      a3 * rk[un3] + a4 * rk[un4];                           \
        }                                                                    \
    }
#define FOLD8(src, KC)                                                       \
    {                                                                        \
        const float* wk = wl_h + (KC) * 8;                                   \
        _Pragma("unroll")                                                    \
        for (int c = 0; c < 32; ++c) {                                       \
            gpart[c] += wk[c * 32 + 0] * src[0] + wk[c * 32 + 1] * src[1] +  \
                        wk[c * 32 + 2] * src[2] + wk[c * 32 + 3] * src[3] +  \
                        wk[c * 32 + 4] * src[4] + wk[c * 32 + 5] * src[5] +  \
                        wk[c * 32 + 6] * src[6] + wk[c * 32 + 7] * src[7];   \
        }                                                                    \
    }

    {
        float r0[8], r1[8];
        STEN8(r0, 0);
        STEN8(r1, 1);      // next batch in flight before first fold
        FOLD8(r0, 0);
        STEN8(r0, 2);
        FOLD8(r1, 1);
        STEN8(r1, 3);
        FOLD8(r0, 2);
        FOLD8(r1, 3);
    }
#undef STEN8
#undef FOLD8

    // ---- head-reduce in c-quarters, fully unrolled (static gpart idx) ----
#pragma unroll
    for (int q = 0; q < 4; ++q) {
#pragma unroll
        for (int cq = 0; cq < 8; ++cq) gp[h][cq][nd] = gpart[q * 8 + cq];
        __syncthreads();
#pragma unroll
        for (int t2 = 0; t2 < 2; ++t2) {
            int cq = h * 2 + t2;
            gout[q * 8 + cq][nd] = gp[0][cq][nd] + gp[1][cq][nd] +
                                   gp[2][cq][nd] + gp[3][cq][nd];
        }
        __syncthreads();
    }

    // ---- restore conv + residual + BN partials: wave owns 16 out-ch ----
    {
        float gv[32];
#pragma unroll
        for (int c = 0; c < 32; ++c) gv[c] = gout[c][nd];
        const float* xb = x + (size_t)b * CINC * NN + v0 + nd;
        float* ob = outp + (size_t)b * CINC * NN + v0 + nd;
        const float* wr_h = w_restore + (size_t)h * 16 * 32;  // SGPR base
#pragma unroll 2
        for (int o16 = 0; o16 < 16; ++o16) {
            int o = h * 16 + o16;
            const float* wr = wr_h + o16 * 32;
            float acc = rb[o];                        // uniform -> s_load
#pragma unroll
            for (int c = 0; c < 32; ++c)
                acc = fmaf(wr[c], gv[c], acc);
            acc += xb[(size_t)o * NN];               // residual
            ob[(size_t)o * NN] = acc;
            float r1 = acc, r2 = acc * acc;
#pragma unroll
            for (int off = 32; off > 0; off >>= 1) {
                r1 += __shfl_xor(r1, off, 64);
                r2 += __shfl_xor(r2, off, 64);
            }
            if (nd == 0) { stat_lds[o] = r1; stat_lds[64 + o] = r2; }
        }
    }
    __syncthreads();
    if (tid < 128) part[(size_t)s * 128 + tid] = stat_lds[tid];  // coalesced
}

// ---------------------------------------------------------------------------
// k2b: reduce per-block partials (2048 x 128, L2-resident) -> stats[128]
// ---------------------------------------------------------------------------
__global__ __launch_bounds__(256) void gat_k2b(
        const float* __restrict__ part, float* __restrict__ stats) {
    __shared__ float red[4];
    int jj = blockIdx.x;       // 0..127: stat index
    int tid = threadIdx.x;
    float acc = 0.f;
    for (int s = tid; s < 2048; s += 256) acc += part[(size_t)s * 128 + jj];
#pragma unroll
    for (int off = 32; off > 0; off >>= 1) acc += __shfl_xor(acc, off, 64);
    int wv = tid >> 6, lane = tid & 63;
    if (lane == 0) red[wv] = acc;
    __syncthreads();
    if (tid == 0) stats[jj] = red[0] + red[1] + red[2] + red[3];
}

// ---------------------------------------------------------------------------
// k3: BN (batch stats) + ReLU, in place on d_out. float4 per thread.
// ---------------------------------------------------------------------------
__global__ __launch_bounds__(256) void gat_k3(
        float* __restrict__ out, const float* __restrict__ stats,
        const float* __restrict__ gamma, const float* __restrict__ beta) {
    int f = blockIdx.x * 256 + threadIdx.x;
    int e = f * 4;
    int c = (e >> 14) & 63;
    const float cnt_inv = 1.f / 131072.f;   // B*H*W
    float mean = stats[c] * cnt_inv;
    float var = stats[64 + c] * cnt_inv - mean * mean;
    float inv = rsqrtf(var + 1e-5f);
    float sc = gamma[c] * inv;
    float sh = beta[c] - mean * sc;
    float4 vv = reinterpret_cast<float4*>(out)[f];
    vv.x = fmaxf(vv.x * sc + sh, 0.f);
    vv.y = fmaxf(vv.y * sc + sh, 0.f);
    vv.z = fmaxf(vv.z * sc + sh, 0.f);
    vv.w = fmaxf(vv.w * sc + sh, 0.f);
    reinterpret_cast<float4*>(out)[f] = vv;
}

// ---------------------------------------------------------------------------
extern "C" void kernel_launch(void* const* d_in, const int* in_sizes, int n_in,
                              void* d_out, int out_size, void* d_ws, size_t ws_size,
                              hipStream_t stream) {
    const float* x         = (const float*)d_in[0];
    const float* w_reduce  = (const float*)d_in[1];
    const float* w_lin     = (const float*)d_in[2];
    const float* att_src   = (const float*)d_in[3];
    const float* att_dst   = (const float*)d_in[4];
    const float* b_gat     = (const float*)d_in[5];
    const float* w_restore = (const float*)d_in[6];
    const float* bn_gamma  = (const float*)d_in[7];
    const float* bn_beta   = (const float*)d_in[8];
    // src/dst (d_in[9], d_in[10]) unused: the grid structure is known.

    float* ws     = (float*)d_ws;
    float* red_g  = ws;                       // 8*32*16384 = 4,194,304
    float* as_ws  = red_g + 4194304;          // 524,288
    float* ad_ws  = as_ws + 524288;           // 524,288
    float* Sf     = ad_ws + 524288;           // 128
    float* Df     = Sf + 128;                 // 128
    float* rbf    = Df + 128;                 // 64
    float* wredT  = rbf + 64;                 // 2048
    float* stats  = wredT + 2048;             // 128
    float* part   = stats + 128;              // 2048*128 = 262,144

    gat_k0<<<1, 256, 0, stream>>>(w_restore, b_gat, w_reduce, w_lin,
                                  att_src, att_dst, rbf, wredT, Sf, Df);
    gat_k1<<<2048, 256, 0, stream>>>(x, wredT, Sf, Df, red_g, as_ws, ad_ws);
    gat_k2<<<2048, 256, 0, stream>>>(x, w_lin, w_restore, rbf, red_g,
                                     as_ws, ad_ws, (float*)d_out, part);
    gat_k2b<<<128, 256, 0, stream>>>(part, stats);
    gat_k3<<<8192, 256, 0, stream>>>((float*)d_out, stats, bn_gamma, bn_beta);
}

// Round 17
// 123.388 us; speedup vs baseline: 1.2345x; 1.2345x over previous
//
#include <hip/hip_runtime.h>

#define NN 16384      // H*W, 128x128
#define CINC 64

typedef float f2 __attribute__((ext_vector_type(2)));

// ---------------------------------------------------------------------------
// k0: fold weights.
// ---------------------------------------------------------------------------
__global__ void gat_k0(const float* __restrict__ w_restore,
                       const float* __restrict__ b_gat,
                       const float* __restrict__ w_reduce,
                       const float* __restrict__ w_lin,
                       const float* __restrict__ att_src,
                       const float* __restrict__ att_dst,
                       float* __restrict__ rb, float* __restrict__ wredT,
                       float* __restrict__ S, float* __restrict__ D) {
    int t = threadIdx.x;
    if (t < 128) {
        int h = t >> 5, k = t & 31;
        float s = 0.f, d = 0.f;
        for (int c = 0; c < 32; ++c) {
            float wl = w_lin[(h * 32 + c) * 32 + k];
            s += att_src[h * 32 + c] * wl;
            d += att_dst[h * 32 + c] * wl;
        }
        S[t] = s; D[t] = d;
    } else if (t < 192) {
        int o = t - 128;
        float r = 0.f;
        for (int c = 0; c < 32; ++c) r += w_restore[o * 32 + c] * b_gat[c];
        rb[o] = r;
    }
    for (int idx = t; idx < 2048; idx += 256) {
        int k = idx & 31, c = idx >> 5;
        wredT[c * 32 + k] = w_reduce[k * 64 + c];
    }
}

// ---------------------------------------------------------------------------
// k1: reduce conv + attention logits. Strip = 64 nodes, 2048 blocks.
// Weights via uniform global reads; inner FMA packed (v_pk_fma_f32).
// ---------------------------------------------------------------------------
__global__ __launch_bounds__(256) void gat_k1(
        const float* __restrict__ x, const float* __restrict__ wredT,
        const float* __restrict__ S, const float* __restrict__ D,
        float* __restrict__ red_g, float* __restrict__ as_ws,
        float* __restrict__ ad_ws) {
    __shared__ float xs[4096];         // [c][nd] 64x64
    __shared__ float red_lds[32][64];  // [k][nd]

    int tid = threadIdx.x;
    int s = blockIdx.x;
    int b = s >> 8;
    int v0 = (s & 255) << 6;

    const float* xb = x + (size_t)b * CINC * NN + v0;
    for (int idx = tid; idx < 4096; idx += 256) {
        int c = idx >> 6, nd = idx & 63;
        xs[idx] = xb[(size_t)c * NN + nd];           // coalesced 256B rows
    }
    __syncthreads();

    int nd = tid & 63;
    int wv = __builtin_amdgcn_readfirstlane(tid >> 6);  // wave-uniform

    // ---- phase A: reduced features, 8 k-channels per wave-group ----
    {
        f2 a2_0 = {0.f, 0.f}, a2_1 = {0.f, 0.f},
           a2_2 = {0.f, 0.f}, a2_3 = {0.f, 0.f};
        const float* wt = wredT + wv * 8;            // uniform base
#pragma unroll 4
        for (int c = 0; c < 64; ++c) {
            float xc = xs[c * 64 + nd];
            f2 x2 = {xc, xc};
            const f2* w2 = reinterpret_cast<const f2*>(wt + c * 32);
            a2_0 = w2[0] * x2 + a2_0;                // v_pk_fma_f32
            a2_1 = w2[1] * x2 + a2_1;
            a2_2 = w2[2] * x2 + a2_2;
            a2_3 = w2[3] * x2 + a2_3;
        }
        int k0 = wv * 8;
        float* rg = red_g + (size_t)b * 32 * NN + v0 + nd;
        red_lds[k0 + 0][nd] = a2_0.x; rg[(size_t)(k0 + 0) * NN] = a2_0.x;
        red_lds[k0 + 1][nd] = a2_0.y; rg[(size_t)(k0 + 1) * NN] = a2_0.y;
        red_lds[k0 + 2][nd] = a2_1.x; rg[(size_t)(k0 + 2) * NN] = a2_1.x;
        red_lds[k0 + 3][nd] = a2_1.y; rg[(size_t)(k0 + 3) * NN] = a2_1.y;
        red_lds[k0 + 4][nd] = a2_2.x; rg[(size_t)(k0 + 4) * NN] = a2_2.x;
        red_lds[k0 + 5][nd] = a2_2.y; rg[(size_t)(k0 + 5) * NN] = a2_2.y;
        red_lds[k0 + 6][nd] = a2_3.x; rg[(size_t)(k0 + 6) * NN] = a2_3.x;
        red_lds[k0 + 7][nd] = a2_3.y; rg[(size_t)(k0 + 7) * NN] = a2_3.y;
    }
    __syncthreads();

    // ---- phase B: logits, head = wave; packed dot products ----
    {
        f2 rv2[16];
#pragma unroll
        for (int k2 = 0; k2 < 16; ++k2)
            rv2[k2] = f2{red_lds[2 * k2][nd], red_lds[2 * k2 + 1][nd]};
        const f2* sp2 = reinterpret_cast<const f2*>(S + wv * 32);
        const f2* dp2 = reinterpret_cast<const f2*>(D + wv * 32);
        f2 pas2 = {0.f, 0.f}, pad2 = {0.f, 0.f};
#pragma unroll
        for (int k2 = 0; k2 < 16; ++k2) {
            pas2 = sp2[k2] * rv2[k2] + pas2;
            pad2 = dp2[k2] * rv2[k2] + pad2;
        }
        as_ws[((size_t)b * 4 + wv) * NN + v0 + nd] = pas2.x + pas2.y;
        ad_ws[((size_t)b * 4 + wv) * NN + v0 + nd] = pad2.x + pad2.y;
    }
}

// ---------------------------------------------------------------------------
// k2: round-12 structure with fold/restore in PACKED FP32 (v_pk_fma_f32 --
//     halves the dominant VALU instruction count: fold 1024->512+32,
//     restore 512->256+16). Weight pairs are memory-adjacent -> SGPR pairs
//     (VOP3P allows one scalar source). gacc2[32] f2 accumulators (+32 VGPR,
//     still < 128). Everything else identical to round-12 (63us best).
// ---------------------------------------------------------------------------
__global__ __launch_bounds__(256) void gat_k2(
        const float* __restrict__ x, const float* __restrict__ w_lin,
        const float* __restrict__ w_restore, const float* __restrict__ rb,
        const float* __restrict__ red_g, const float* __restrict__ as_ws,
        const float* __restrict__ ad_ws, float* __restrict__ outp,
        float* __restrict__ part) {
    __shared__ float gp[4][8][64];    // per-head partial, c-quarter: 8 KB
    __shared__ float gout[32][64];    // reduced g: 8 KB
    __shared__ float stat_lds[128];

    int tid = threadIdx.x;
    int s = blockIdx.x;
    int b = s >> 8;
    int v0 = (s & 255) << 6;
    int nd = tid & 63;
    int h = __builtin_amdgcn_readfirstlane(tid >> 6);  // wave-uniform head
    int v = v0 + nd;
    int i = v >> 7, j = v & 127;

    int un0 = v;
    int un1 = i > 0   ? v - 128 : v;
    int un2 = i < 127 ? v + 128 : v;
    int un3 = j > 0   ? v - 1   : v;
    int un4 = j < 127 ? v + 1   : v;

    // ---- alpha (regs only), head = wave ----
    float a0, a1, a2, a3, a4;
    {
        const float* asp = as_ws + ((size_t)b * 4 + h) * NN;
        float adv = ad_ws[((size_t)b * 4 + h) * NN + v];
        float e0 = asp[un0] + adv, e1 = asp[un1] + adv, e2 = asp[un2] + adv,
              e3 = asp[un3] + adv, e4 = asp[un4] + adv;
        e0 = e0 > 0.f ? e0 : 0.2f * e0;
        e1 = e1 > 0.f ? e1 : 0.2f * e1;
        e2 = e2 > 0.f ? e2 : 0.2f * e2;
        e3 = e3 > 0.f ? e3 : 0.2f * e3;
        e4 = e4 > 0.f ? e4 : 0.2f * e4;
        e1 += i > 0   ? 0.f : -1e30f;
        e2 += i < 127 ? 0.f : -1e30f;
        e3 += j > 0   ? 0.f : -1e30f;
        e4 += j < 127 ? 0.f : -1e30f;
        float m = fmaxf(fmaxf(fmaxf(e0, e1), fmaxf(e2, e3)), e4);
        e0 = __expf(e0 - m); e1 = __expf(e1 - m); e2 = __expf(e2 - m);
        e3 = __expf(e3 - m); e4 = __expf(e4 - m);
        float sc = 0.25f / (e0 + e1 + e2 + e3 + e4);   // fold head-mean
        a0 = e0 * sc; a1 = e1 * sc; a2 = e2 * sc; a3 = e3 * sc; a4 = e4 * sc;
    }

    // ---- stencil (r12 kc structure) + PACKED SGPR fold ----
    f2 gacc2[32];
#pragma unroll
    for (int c = 0; c < 32; ++c) gacc2[c] = f2{0.f, 0.f};

    const float* rp = red_g + (size_t)b * 32 * NN;
    const float* wl_h = w_lin + (size_t)h * 32 * 32;   // SGPR base
#pragma unroll 1
    for (int kc = 0; kc < 4; ++kc) {
        float racc8[8];
#pragma unroll
        for (int i8 = 0; i8 < 8; ++i8) {
            const float* rk = rp + (size_t)(kc * 8 + i8) * NN;
            racc8[i8] = a0 * rk[un0] + a1 * rk[un1] + a2 * rk[un2] +
                        a3 * rk[un3] + a4 * rk[un4];      // coalesced b32 x5
        }
        f2 r2_0 = {racc8[0], racc8[1]}, r2_1 = {racc8[2], racc8[3]},
           r2_2 = {racc8[4], racc8[5]}, r2_3 = {racc8[6], racc8[7]};
#pragma unroll
        for (int c = 0; c < 32; ++c) {
            const f2* wk2 =
                reinterpret_cast<const f2*>(wl_h + c * 32 + kc * 8);
            f2 t = gacc2[c];
            t = wk2[0] * r2_0 + t;                    // v_pk_fma_f32
            t = wk2[1] * r2_1 + t;
            t = wk2[2] * r2_2 + t;
            t = wk2[3] * r2_3 + t;
            gacc2[c] = t;
        }
    }

    // ---- head-reduce in c-quarters, fully unrolled (static indices) ----
#pragma unroll
    for (int q = 0; q < 4; ++q) {
#pragma unroll
        for (int cq = 0; cq < 8; ++cq) {
            f2 g2 = gacc2[q * 8 + cq];
            gp[h][cq][nd] = g2.x + g2.y;              // horizontal add here
        }
        __syncthreads();
#pragma unroll
        for (int t2 = 0; t2 < 2; ++t2) {
            int cq = h * 2 + t2;
            gout[q * 8 + cq][nd] = gp[0][cq][nd] + gp[1][cq][nd] +
                                   gp[2][cq][nd] + gp[3][cq][nd];
        }
        __syncthreads();
    }

    // ---- restore conv (packed) + residual + BN partials ----
    {
        f2 gv2[16];
#pragma unroll
        for (int p = 0; p < 16; ++p)
            gv2[p] = f2{gout[2 * p][nd], gout[2 * p + 1][nd]};
        const float* xb = x + (size_t)b * CINC * NN + v0 + nd;
        float* ob = outp + (size_t)b * CINC * NN + v0 + nd;
        const float* wr_h = w_restore + (size_t)h * 16 * 32;  // SGPR base
#pragma unroll 2
        for (int o16 = 0; o16 < 16; ++o16) {
            int o = h * 16 + o16;
            const f2* wr2 = reinterpret_cast<const f2*>(wr_h + o16 * 32);
            f2 acc2 = {0.f, 0.f};
#pragma unroll
            for (int p = 0; p < 16; ++p)
                acc2 = wr2[p] * gv2[p] + acc2;        // v_pk_fma_f32
            float acc = rb[o] + acc2.x + acc2.y;
            acc += xb[(size_t)o * NN];                // residual
            ob[(size_t)o * NN] = acc;
            float r1 = acc, r2 = acc * acc;
#pragma unroll
            for (int off = 32; off > 0; off >>= 1) {
                r1 += __shfl_xor(r1, off, 64);
                r2 += __shfl_xor(r2, off, 64);
            }
            if (nd == 0) { stat_lds[o] = r1; stat_lds[64 + o] = r2; }
        }
    }
    __syncthreads();
    if (tid < 128) part[(size_t)s * 128 + tid] = stat_lds[tid];  // coalesced
}

// ---------------------------------------------------------------------------
// k2b: reduce per-block partials (2048 x 128, L2-resident) -> stats[128]
// ---------------------------------------------------------------------------
__global__ __launch_bounds__(256) void gat_k2b(
        const float* __restrict__ part, float* __restrict__ stats) {
    __shared__ float red[4];
    int jj = blockIdx.x;       // 0..127: stat index
    int tid = threadIdx.x;
    float acc = 0.f;
    for (int s = tid; s < 2048; s += 256) acc += part[(size_t)s * 128 + jj];
#pragma unroll
    for (int off = 32; off > 0; off >>= 1) acc += __shfl_xor(acc, off, 64);
    int wv = tid >> 6, lane = tid & 63;
    if (lane == 0) red[wv] = acc;
    __syncthreads();
    if (tid == 0) stats[jj] = red[0] + red[1] + red[2] + red[3];
}

// ---------------------------------------------------------------------------
// k3: BN (batch stats) + ReLU, in place on d_out. float4 per thread.
// ---------------------------------------------------------------------------
__global__ __launch_bounds__(256) void gat_k3(
        float* __restrict__ out, const float* __restrict__ stats,
        const float* __restrict__ gamma, const float* __restrict__ beta) {
    int f = blockIdx.x * 256 + threadIdx.x;
    int e = f * 4;
    int c = (e >> 14) & 63;
    const float cnt_inv = 1.f / 131072.f;   // B*H*W
    float mean = stats[c] * cnt_inv;
    float var = stats[64 + c] * cnt_inv - mean * mean;
    float inv = rsqrtf(var + 1e-5f);
    float sc = gamma[c] * inv;
    float sh = beta[c] - mean * sc;
    float4 vv = reinterpret_cast<float4*>(out)[f];
    vv.x = fmaxf(vv.x * sc + sh, 0.f);
    vv.y = fmaxf(vv.y * sc + sh, 0.f);
    vv.z = fmaxf(vv.z * sc + sh, 0.f);
    vv.w = fmaxf(vv.w * sc + sh, 0.f);
    reinterpret_cast<float4*>(out)[f] = vv;
}

// ---------------------------------------------------------------------------
extern "C" void kernel_launch(void* const* d_in, const int* in_sizes, int n_in,
                              void* d_out, int out_size, void* d_ws, size_t ws_size,
                              hipStream_t stream) {
    const float* x         = (const float*)d_in[0];
    const float* w_reduce  = (const float*)d_in[1];
    const float* w_lin     = (const float*)d_in[2];
    const float* att_src   = (const float*)d_in[3];
    const float* att_dst   = (const float*)d_in[4];
    const float* b_gat     = (const float*)d_in[5];
    const float* w_restore = (const float*)d_in[6];
    const float* bn_gamma  = (const float*)d_in[7];
    const float* bn_beta   = (const float*)d_in[8];
    // src/dst (d_in[9], d_in[10]) unused: the grid structure is known.

    float* ws     = (float*)d_ws;
    float* red_g  = ws;                       // 8*32*16384 = 4,194,304
    float* as_ws  = red_g + 4194304;          // 524,288
    float* ad_ws  = as_ws + 524288;           // 524,288
    float* Sf     = ad_ws + 524288;           // 128
    float* Df     = Sf + 128;                 // 128
    float* rbf    = Df + 128;                 // 64
    float* wredT  = rbf + 64;                 // 2048
    float* stats  = wredT + 2048;             // 128
    float* part   = stats + 128;              // 2048*128 = 262,144

    gat_k0<<<1, 256, 0, stream>>>(w_restore, b_gat, w_reduce, w_lin,
                                  att_src, att_dst, rbf, wredT, Sf, Df);
    gat_k1<<<2048, 256, 0, stream>>>(x, wredT, Sf, Df, red_g, as_ws, ad_ws);
    gat_k2<<<2048, 256, 0, stream>>>(x, w_lin, w_restore, rbf, red_g,
                                     as_ws, ad_ws, (float*)d_out, part);
    gat_k2b<<<128, 256, 0, stream>>>(part, stats);
    gat_k3<<<8192, 256, 0, stream>>>((float*)d_out, stats, bn_gamma, bn_beta);
}

// Round 18
// 103.020 us; speedup vs baseline: 1.4786x; 1.1977x over previous
//
#include <hip/hip_runtime.h>

#define NN 16384      // H*W, 128x128
#define CINC 64

// ---------------------------------------------------------------------------
// k0: fold weights.
// ---------------------------------------------------------------------------
__global__ void gat_k0(const float* __restrict__ w_restore,
                       const float* __restrict__ b_gat,
                       const float* __restrict__ w_reduce,
                       const float* __restrict__ w_lin,
                       const float* __restrict__ att_src,
                       const float* __restrict__ att_dst,
                       float* __restrict__ rb, float* __restrict__ wredT,
                       float* __restrict__ S, float* __restrict__ D) {
    int t = threadIdx.x;
    if (t < 128) {
        int h = t >> 5, k = t & 31;
        float s = 0.f, d = 0.f;
        for (int c = 0; c < 32; ++c) {
            float wl = w_lin[(h * 32 + c) * 32 + k];
            s += att_src[h * 32 + c] * wl;
            d += att_dst[h * 32 + c] * wl;
        }
        S[t] = s; D[t] = d;
    } else if (t < 192) {
        int o = t - 128;
        float r = 0.f;
        for (int c = 0; c < 32; ++c) r += w_restore[o * 32 + c] * b_gat[c];
        rb[o] = r;
    }
    for (int idx = t; idx < 2048; idx += 256) {
        int k = idx & 31, c = idx >> 5;
        wredT[c * 32 + k] = w_reduce[k * 64 + c];
    }
}

// ---------------------------------------------------------------------------
// k1: reduce conv + attention logits. Strip = 64 nodes, 2048 blocks.
// Weights via uniform global reads (s_load / constant cache). (round-12)
// ---------------------------------------------------------------------------
__global__ __launch_bounds__(256) void gat_k1(
        const float* __restrict__ x, const float* __restrict__ wredT,
        const float* __restrict__ S, const float* __restrict__ D,
        float* __restrict__ red_g, float* __restrict__ as_ws,
        float* __restrict__ ad_ws) {
    __shared__ float xs[4096];         // [c][nd] 64x64
    __shared__ float red_lds[32][64];  // [k][nd]

    int tid = threadIdx.x;
    int s = blockIdx.x;
    int b = s >> 8;
    int v0 = (s & 255) << 6;

    const float* xb = x + (size_t)b * CINC * NN + v0;
    for (int idx = tid; idx < 4096; idx += 256) {
        int c = idx >> 6, nd = idx & 63;
        xs[idx] = xb[(size_t)c * NN + nd];           // coalesced 256B rows
    }
    __syncthreads();

    int nd = tid & 63;
    int wv = __builtin_amdgcn_readfirstlane(tid >> 6);  // wave-uniform

    // ---- phase A: reduced features, 8 k-channels per wave-group ----
    {
        float a0 = 0.f, a1 = 0.f, a2 = 0.f, a3 = 0.f,
              a4 = 0.f, a5 = 0.f, a6 = 0.f, a7 = 0.f;
        const float* wt = wredT + wv * 8;            // uniform base
#pragma unroll 4
        for (int c = 0; c < 64; ++c) {
            float xc = xs[c * 64 + nd];
            const float* w = wt + c * 32;            // uniform -> s_load
            a0 = fmaf(w[0], xc, a0);
            a1 = fmaf(w[1], xc, a1);
            a2 = fmaf(w[2], xc, a2);
            a3 = fmaf(w[3], xc, a3);
            a4 = fmaf(w[4], xc, a4);
            a5 = fmaf(w[5], xc, a5);
            a6 = fmaf(w[6], xc, a6);
            a7 = fmaf(w[7], xc, a7);
        }
        int k0 = wv * 8;
        float* rg = red_g + (size_t)b * 32 * NN + v0 + nd;
        red_lds[k0 + 0][nd] = a0; rg[(size_t)(k0 + 0) * NN] = a0;
        red_lds[k0 + 1][nd] = a1; rg[(size_t)(k0 + 1) * NN] = a1;
        red_lds[k0 + 2][nd] = a2; rg[(size_t)(k0 + 2) * NN] = a2;
        red_lds[k0 + 3][nd] = a3; rg[(size_t)(k0 + 3) * NN] = a3;
        red_lds[k0 + 4][nd] = a4; rg[(size_t)(k0 + 4) * NN] = a4;
        red_lds[k0 + 5][nd] = a5; rg[(size_t)(k0 + 5) * NN] = a5;
        red_lds[k0 + 6][nd] = a6; rg[(size_t)(k0 + 6) * NN] = a6;
        red_lds[k0 + 7][nd] = a7; rg[(size_t)(k0 + 7) * NN] = a7;
    }
    __syncthreads();

    // ---- phase B: logits, head = wave; S/D via uniform s_load ----
    {
        float rv[32];
#pragma unroll
        for (int k = 0; k < 32; ++k) rv[k] = red_lds[k][nd];
        const float* sp = S + wv * 32;               // uniform base
        const float* dp = D + wv * 32;
        float pas = 0.f, pad_ = 0.f;
#pragma unroll
        for (int k = 0; k < 32; ++k) {
            pas  = fmaf(sp[k], rv[k], pas);
            pad_ = fmaf(dp[k], rv[k], pad_);
        }
        as_ws[((size_t)b * 4 + wv) * NN + v0 + nd] = pas;
        ad_ws[((size_t)b * 4 + wv) * NN + v0 + nd] = pad_;
    }
}

// ---------------------------------------------------------------------------
// k2: WAVE = K-RANGE (not head). In round-12 all 4 waves loaded the SAME
//     160 red taps (stencil is head-independent; only alpha differs):
//     640 redundant VMEM issues/block, 4x L1 pressure. Now each wave loads
//     only its 8 k-planes (40 loads), computes ALL 4 heads' alphas (cheap),
//     and folds (k,h) pairs into gpart[32] -- total FMA unchanged; the
//     existing gp[4]->gout reduce sums k-partials exactly like h-partials.
//     kc chunks of 2 planes keep round-12's proven 10-load->256-FMA shape.
// ---------------------------------------------------------------------------
__global__ __launch_bounds__(256) void gat_k2(
        const float* __restrict__ x, const float* __restrict__ w_lin,
        const float* __restrict__ w_restore, const float* __restrict__ rb,
        const float* __restrict__ red_g, const float* __restrict__ as_ws,
        const float* __restrict__ ad_ws, float* __restrict__ outp,
        float* __restrict__ part) {
    __shared__ float gp[4][8][64];    // per-wave partial, c-quarter: 8 KB
    __shared__ float gout[32][64];    // reduced g: 8 KB
    __shared__ float stat_lds[128];

    int tid = threadIdx.x;
    int s = blockIdx.x;
    int b = s >> 8;
    int v0 = (s & 255) << 6;
    int nd = tid & 63;
    int wv = __builtin_amdgcn_readfirstlane(tid >> 6);  // wave-uniform k-range
    int v = v0 + nd;
    int i = v >> 7, j = v & 127;

    int un0 = v;
    int un1 = i > 0   ? v - 128 : v;
    int un2 = i < 127 ? v + 128 : v;
    int un3 = j > 0   ? v - 1   : v;
    int un4 = j < 127 ? v + 1   : v;

    // ---- alphas for ALL 4 heads (regs only) ----
    float al[4][5];
#pragma unroll
    for (int h = 0; h < 4; ++h) {
        const float* asp = as_ws + ((size_t)b * 4 + h) * NN;
        float adv = ad_ws[((size_t)b * 4 + h) * NN + v];
        float e0 = asp[un0] + adv, e1 = asp[un1] + adv, e2 = asp[un2] + adv,
              e3 = asp[un3] + adv, e4 = asp[un4] + adv;
        e0 = e0 > 0.f ? e0 : 0.2f * e0;
        e1 = e1 > 0.f ? e1 : 0.2f * e1;
        e2 = e2 > 0.f ? e2 : 0.2f * e2;
        e3 = e3 > 0.f ? e3 : 0.2f * e3;
        e4 = e4 > 0.f ? e4 : 0.2f * e4;
        e1 += i > 0   ? 0.f : -1e30f;
        e2 += i < 127 ? 0.f : -1e30f;
        e3 += j > 0   ? 0.f : -1e30f;
        e4 += j < 127 ? 0.f : -1e30f;
        float m = fmaxf(fmaxf(fmaxf(e0, e1), fmaxf(e2, e3)), e4);
        e0 = __expf(e0 - m); e1 = __expf(e1 - m); e2 = __expf(e2 - m);
        e3 = __expf(e3 - m); e4 = __expf(e4 - m);
        float sc = 0.25f / (e0 + e1 + e2 + e3 + e4);   // fold head-mean
        al[h][0] = e0 * sc; al[h][1] = e1 * sc; al[h][2] = e2 * sc;
        al[h][3] = e3 * sc; al[h][4] = e4 * sc;
    }

    // ---- stencil on this wave's 8 k-planes + fold over (k,h) pairs ----
    float gpart[32];
#pragma unroll
    for (int c = 0; c < 32; ++c) gpart[c] = 0.f;

    const float* rp = red_g + (size_t)b * 32 * NN + (size_t)(wv * 8) * NN;
    const float* wl = w_lin;                       // SGPR base
#pragma unroll 1
    for (int kc = 0; kc < 4; ++kc) {               // 2 k-planes per chunk
        const float* rk0 = rp + (size_t)(kc * 2) * NN;
        const float* rk1 = rk0 + NN;
        float t00 = rk0[un0], t01 = rk0[un1], t02 = rk0[un2],
              t03 = rk0[un3], t04 = rk0[un4];
        float t10 = rk1[un0], t11 = rk1[un1], t12 = rk1[un2],
              t13 = rk1[un3], t14 = rk1[un4];      // 10 coalesced loads
        float r0[4], r1[4];
#pragma unroll
        for (int h = 0; h < 4; ++h) {
            r0[h] = al[h][0] * t00 + al[h][1] * t01 + al[h][2] * t02 +
                    al[h][3] * t03 + al[h][4] * t04;
            r1[h] = al[h][0] * t10 + al[h][1] * t11 + al[h][2] * t12 +
                    al[h][3] * t13 + al[h][4] * t14;
        }
#pragma unroll
        for (int c = 0; c < 32; ++c) {
#pragma unroll
            for (int h = 0; h < 4; ++h) {
                // uniform addr: wv*8 wave-uniform, rest compile-time -> s_load
                const float* wk = wl + (h * 32 + c) * 32 + wv * 8 + kc * 2;
                gpart[c] += wk[0] * r0[h] + wk[1] * r1[h];
            }
        }
    }

    // ---- reduce 4 wave-partials in c-quarters (static gpart idx) ----
#pragma unroll
    for (int q = 0; q < 4; ++q) {
#pragma unroll
        for (int cq = 0; cq < 8; ++cq) gp[wv][cq][nd] = gpart[q * 8 + cq];
        __syncthreads();
#pragma unroll
        for (int t2 = 0; t2 < 2; ++t2) {
            int cq = wv * 2 + t2;
            gout[q * 8 + cq][nd] = gp[0][cq][nd] + gp[1][cq][nd] +
                                   gp[2][cq][nd] + gp[3][cq][nd];
        }
        __syncthreads();
    }

    // ---- restore conv + residual + BN partials: wave owns 16 out-ch ----
    {
        float gv[32];
#pragma unroll
        for (int c = 0; c < 32; ++c) gv[c] = gout[c][nd];
        const float* xb = x + (size_t)b * CINC * NN + v0 + nd;
        float* ob = outp + (size_t)b * CINC * NN + v0 + nd;
        const float* wr_h = w_restore + (size_t)wv * 16 * 32;  // SGPR base
#pragma unroll 2
        for (int o16 = 0; o16 < 16; ++o16) {
            int o = wv * 16 + o16;
            const float* wr = wr_h + o16 * 32;
            float acc = rb[o];                        // uniform -> s_load
#pragma unroll
            for (int c = 0; c < 32; ++c)
                acc = fmaf(wr[c], gv[c], acc);
            acc += xb[(size_t)o * NN];               // residual
            ob[(size_t)o * NN] = acc;
            float r1 = acc, r2 = acc * acc;
#pragma unroll
            for (int off = 32; off > 0; off >>= 1) {
                r1 += __shfl_xor(r1, off, 64);
                r2 += __shfl_xor(r2, off, 64);
            }
            if (nd == 0) { stat_lds[o] = r1; stat_lds[64 + o] = r2; }
        }
    }
    __syncthreads();
    if (tid < 128) part[(size_t)s * 128 + tid] = stat_lds[tid];  // coalesced
}

// ---------------------------------------------------------------------------
// k2b: reduce per-block partials (2048 x 128, L2-resident) -> stats[128]
// ---------------------------------------------------------------------------
__global__ __launch_bounds__(256) void gat_k2b(
        const float* __restrict__ part, float* __restrict__ stats) {
    __shared__ float red[4];
    int jj = blockIdx.x;       // 0..127: stat index
    int tid = threadIdx.x;
    float acc = 0.f;
    for (int s = tid; s < 2048; s += 256) acc += part[(size_t)s * 128 + jj];
#pragma unroll
    for (int off = 32; off > 0; off >>= 1) acc += __shfl_xor(acc, off, 64);
    int wv = tid >> 6, lane = tid & 63;
    if (lane == 0) red[wv] = acc;
    __syncthreads();
    if (tid == 0) stats[jj] = red[0] + red[1] + red[2] + red[3];
}

// ---------------------------------------------------------------------------
// k3: BN (batch stats) + ReLU, in place on d_out. float4 per thread.
// ---------------------------------------------------------------------------
__global__ __launch_bounds__(256) void gat_k3(
        float* __restrict__ out, const float* __restrict__ stats,
        const float* __restrict__ gamma, const float* __restrict__ beta) {
    int f = blockIdx.x * 256 + threadIdx.x;
    int e = f * 4;
    int c = (e >> 14) & 63;
    const float cnt_inv = 1.f / 131072.f;   // B*H*W
    float mean = stats[c] * cnt_inv;
    float var = stats[64 + c] * cnt_inv - mean * mean;
    float inv = rsqrtf(var + 1e-5f);
    float sc = gamma[c] * inv;
    float sh = beta[c] - mean * sc;
    float4 vv = reinterpret_cast<float4*>(out)[f];
    vv.x = fmaxf(vv.x * sc + sh, 0.f);
    vv.y = fmaxf(vv.y * sc + sh, 0.f);
    vv.z = fmaxf(vv.z * sc + sh, 0.f);
    vv.w = fmaxf(vv.w * sc + sh, 0.f);
    reinterpret_cast<float4*>(out)[f] = vv;
}

// ---------------------------------------------------------------------------
extern "C" void kernel_launch(void* const* d_in, const int* in_sizes, int n_in,
                              void* d_out, int out_size, void* d_ws, size_t ws_size,
                              hipStream_t stream) {
    const float* x         = (const float*)d_in[0];
    const float* w_reduce  = (const float*)d_in[1];
    const float* w_lin     = (const float*)d_in[2];
    const float* att_src   = (const float*)d_in[3];
    const float* att_dst   = (const float*)d_in[4];
    const float* b_gat     = (const float*)d_in[5];
    const float* w_restore = (const float*)d_in[6];
    const float* bn_gamma  = (const float*)d_in[7];
    const float* bn_beta   = (const float*)d_in[8];
    // src/dst (d_in[9], d_in[10]) unused: the grid structure is known.

    float* ws     = (float*)d_ws;
    float* red_g  = ws;                       // 8*32*16384 = 4,194,304
    float* as_ws  = red_g + 4194304;          // 524,288
    float* ad_ws  = as_ws + 524288;           // 524,288
    float* Sf     = ad_ws + 524288;           // 128
    float* Df     = Sf + 128;                 // 128
    float* rbf    = Df + 128;                 // 64
    float* wredT  = rbf + 64;                 // 2048
    float* stats  = wredT + 2048;             // 128
    float* part   = stats + 128;              // 2048*128 = 262,144

    gat_k0<<<1, 256, 0, stream>>>(w_restore, b_gat, w_reduce, w_lin,
                                  att_src, att_dst, rbf, wredT, Sf, Df);
    gat_k1<<<2048, 256, 0, stream>>>(x, wredT, Sf, Df, red_g, as_ws, ad_ws);
    gat_k2<<<2048, 256, 0, stream>>>(x, w_lin, w_restore, rbf, red_g,
                                     as_ws, ad_ws, (float*)d_out, part);
    gat_k2b<<<128, 256, 0, stream>>>(part, stats);
    gat_k3<<<8192, 256, 0, stream>>>((float*)d_out, stats, bn_gamma, bn_beta);
}